// Round 5
// baseline (308.597 us; speedup 1.0000x reference)
//
#include <hip/hip_runtime.h>
#include <hip/hip_bf16.h>

#define NB   4      // batch
#define CIN  512    // in channels
#define NPX  16384  // H*W
#define KC   256    // key channels
#define KP   150    // proxy regions

// LDS row strides (u16 units). All multiples of 8 (16B alignment for b128),
// and ≡4 mod 32 dwords so consecutive rows shift 4 banks -> b128 reads hit
// the uniform bank floor (no conflicts beyond the 8-round b128 minimum).
#define LDH  264    // H1/Q/CX rows [128][256] padded
#define LDP  200    // P rows [128][160] padded
#define LDX  72     // XB rows [128][64] padded
#define SHSZ 33792  // u16: 128*264 = 67584 B total LDS
#define XBOF 15360  // XB dbuf base (2 x 9216 u16), overlaid inside H1 region

typedef __attribute__((ext_vector_type(8))) short short8;
typedef __attribute__((ext_vector_type(4))) float f32x4;
typedef __attribute__((ext_vector_type(4))) unsigned int u32x4;
typedef unsigned short u16;

__device__ __forceinline__ u16 f2bf(float f) {
    unsigned int u = __float_as_uint(f);
    return (u16)((u + 0x7FFFu + ((u >> 16) & 1u)) >> 16);
}
__device__ __forceinline__ unsigned pk2(float a, float b) {
    return (unsigned)f2bf(a) | ((unsigned)f2bf(b) << 16);
}
// fragment load from pre-packed global: idx = (R*NS+S)*64 + lane
__device__ __forceinline__ short8 ldfrag(const u16* __restrict__ p, int idx) {
    return *(const short8*)(p + ((long)idx << 3));
}

// ===========================================================================
// Fused: x(fp32) -> G1 -> G2 -> G3 -> softmax -> G4 -> G5 -> out(fp32)
// per 128-pixel tile. 512 thr = 8 waves (4 mg x 2 ng). 66KB LDS, 2 blk/CU.
// All A-operands read as packed frags from global (L2); LDS = pixel data only.
// ===========================================================================
__global__ __launch_bounds__(512, 4)
void fused_kernel(const u16* __restrict__ wp1p, const float* __restrict__ xg,
                  const u16* __restrict__ wp2p, const float* __restrict__ bp1,
                  const float* __restrict__ bp2, const u16* __restrict__ keyp,
                  const u16* __restrict__ vp, const u16* __restrict__ wup,
                  const float* __restrict__ bu, float* __restrict__ outg)
{
    __shared__ u16 sh[SHSZ];

    const int b  = blockIdx.z;
    const int n0 = blockIdx.x * 128;
    const int tid = threadIdx.x, lane = tid & 63, wid = tid >> 6;
    const int rg = lane & 15, kg = lane >> 4;
    const int mg = wid >> 1, ng = wid & 1;

    const float* xb = xg + (long)b * CIN * NPX;
    float* ob       = outg + (long)b * CIN * NPX;
    const u16* kyp  = keyp + (long)b * 40960;
    const u16* vbp  = vp   + (long)b * 40960;

    // ------------------------- phase 1: G1 (K=512) -------------------------
    const int sxn = tid & 127, sxk = tid >> 7;
    const float* xsrc = xb + (long)(sxk * 16) * NPX + n0 + sxn;
    u16* XB = sh + XBOF;

    float xr[16];
    auto LOADX = [&](int kt) {
        #pragma unroll
        for (int e = 0; e < 16; ++e)
            xr[e] = xsrc[(long)(kt * 64 + e) * NPX];
    };
    auto WRITE_XB = [&](int buf) {
        #pragma unroll
        for (int h = 0; h < 2; ++h) {
            u32x4 v;
            v.x = pk2(xr[h * 8 + 0], xr[h * 8 + 1]);
            v.y = pk2(xr[h * 8 + 2], xr[h * 8 + 3]);
            v.z = pk2(xr[h * 8 + 4], xr[h * 8 + 5]);
            v.w = pk2(xr[h * 8 + 6], xr[h * 8 + 7]);
            *(u32x4*)(XB + buf * 9216 + sxn * LDX + (sxk * 2 + h) * 8) = v;
        }
    };

    f32x4 acc[4][4];
    #pragma unroll
    for (int i = 0; i < 4; ++i)
        #pragma unroll
        for (int j = 0; j < 4; ++j) acc[i][j] = (f32x4){0.f, 0.f, 0.f, 0.f};

    LOADX(0); WRITE_XB(0);
    __syncthreads();

    for (int kt = 0; kt < 8; ++kt) {
        const int buf = kt & 1;
        if (kt < 7) LOADX(kt + 1);
        #pragma unroll
        for (int s = 0; s < 2; ++s) {
            short8 a[4], bb[4];
            #pragma unroll
            for (int i = 0; i < 4; ++i)
                a[i] = ldfrag(wp1p, ((mg * 4 + i) * 16 + kt * 2 + s) * 64 + lane);
            #pragma unroll
            for (int j = 0; j < 4; ++j)
                bb[j] = *(const short8*)(XB + buf * 9216 + (ng * 64 + j * 16 + rg) * LDX + (s * 4 + kg) * 8);
            #pragma unroll
            for (int i = 0; i < 4; ++i)
                #pragma unroll
                for (int j = 0; j < 4; ++j)
                    acc[i][j] = __builtin_amdgcn_mfma_f32_16x16x32_bf16(a[i], bb[j], acc[i][j], 0, 0, 0);
        }
        if (kt < 7) WRITE_XB(buf ^ 1);
        __syncthreads();
    }

    // h1 -> LDS [n][kc] (stride LDH), bias+relu
    #pragma unroll
    for (int i = 0; i < 4; ++i) {
        const int kc4 = mg * 64 + i * 16 + kg * 4;
        const f32x4 bv = *(const f32x4*)(bp1 + kc4);
        #pragma unroll
        for (int j = 0; j < 4; ++j) {
            const int n = ng * 64 + j * 16 + rg;
            uint2 pk;
            pk.x = pk2(fmaxf(acc[i][j][0] + bv.x, 0.f), fmaxf(acc[i][j][1] + bv.y, 0.f));
            pk.y = pk2(fmaxf(acc[i][j][2] + bv.z, 0.f), fmaxf(acc[i][j][3] + bv.w, 0.f));
            *(uint2*)(sh + n * LDH + kc4) = pk;
        }
    }
    __syncthreads();

    // ------------------------- phase 2: G2 (K=256) -------------------------
    f32x4 acc2[4][4];
    #pragma unroll
    for (int i = 0; i < 4; ++i)
        #pragma unroll
        for (int j = 0; j < 4; ++j) acc2[i][j] = (f32x4){0.f, 0.f, 0.f, 0.f};

    for (int S = 0; S < 8; ++S) {
        short8 a[4], bb[4];
        #pragma unroll
        for (int i = 0; i < 4; ++i)
            a[i] = ldfrag(wp2p, ((mg * 4 + i) * 8 + S) * 64 + lane);
        #pragma unroll
        for (int j = 0; j < 4; ++j)
            bb[j] = *(const short8*)(sh + (ng * 64 + j * 16 + rg) * LDH + S * 32 + kg * 8);
        #pragma unroll
        for (int i = 0; i < 4; ++i)
            #pragma unroll
            for (int j = 0; j < 4; ++j)
                acc2[i][j] = __builtin_amdgcn_mfma_f32_16x16x32_bf16(a[i], bb[j], acc2[i][j], 0, 0, 0);
    }
    __syncthreads();   // all H1 reads done

    // q2 -> same LDS region, bias+relu
    #pragma unroll
    for (int i = 0; i < 4; ++i) {
        const int kc4 = mg * 64 + i * 16 + kg * 4;
        const f32x4 bv = *(const f32x4*)(bp2 + kc4);
        #pragma unroll
        for (int j = 0; j < 4; ++j) {
            const int n = ng * 64 + j * 16 + rg;
            uint2 pk;
            pk.x = pk2(fmaxf(acc2[i][j][0] + bv.x, 0.f), fmaxf(acc2[i][j][1] + bv.y, 0.f));
            pk.y = pk2(fmaxf(acc2[i][j][2] + bv.z, 0.f), fmaxf(acc2[i][j][3] + bv.w, 0.f));
            *(uint2*)(sh + n * LDH + kc4) = pk;
        }
    }
    __syncthreads();

    // ------------------- phase 3: G3 + in-register softmax ------------------
    // wave wid owns pixels n = wid*16 + rg
    f32x4 s1[10];
    #pragma unroll
    for (int i = 0; i < 10; ++i) s1[i] = (f32x4){0.f, 0.f, 0.f, 0.f};
    for (int s = 0; s < 8; ++s) {
        short8 bq = *(const short8*)(sh + (wid * 16 + rg) * LDH + s * 32 + kg * 8);
        #pragma unroll
        for (int i = 0; i < 10; ++i) {
            short8 a = ldfrag(kyp, (i * 8 + s) * 64 + lane);
            s1[i] = __builtin_amdgcn_mfma_f32_16x16x32_bf16(a, bq, s1[i], 0, 0, 0);
        }
    }
    float mx = -3.0e38f;
    #pragma unroll
    for (int i = 0; i < 9; ++i)
        #pragma unroll
        for (int r = 0; r < 4; ++r) mx = fmaxf(mx, s1[i][r]);
    #pragma unroll
    for (int r = 0; r < 4; ++r) if (kg * 4 + r < 6) mx = fmaxf(mx, s1[9][r]);
    mx = fmaxf(mx, __shfl_xor(mx, 16));
    mx = fmaxf(mx, __shfl_xor(mx, 32));
    float l = 0.f;
    #pragma unroll
    for (int i = 0; i < 10; ++i)
        #pragma unroll
        for (int r = 0; r < 4; ++r) {
            const bool valid = (i < 9) || (kg * 4 + r < 6);
            float e = valid ? __expf((s1[i][r] - mx) * 0.0625f) : 0.f;
            s1[i][r] = e; l += e;
        }
    l += __shfl_xor(l, 16);
    l += __shfl_xor(l, 32);
    const float inv = 1.f / l;
    __syncthreads();   // all Q reads done

    // P -> LDS [n][kp] (stride LDP), normalized bf16
    #pragma unroll
    for (int i = 0; i < 10; ++i) {
        uint2 pk;
        pk.x = pk2(s1[i][0] * inv, s1[i][1] * inv);
        pk.y = pk2(s1[i][2] * inv, s1[i][3] * inv);
        *(uint2*)(sh + (wid * 16 + rg) * LDP + i * 16 + kg * 4) = pk;
    }
    __syncthreads();

    // ------------------------- phase 4: G4 (K=160) -------------------------
    f32x4 acc4[4][4];
    #pragma unroll
    for (int i = 0; i < 4; ++i)
        #pragma unroll
        for (int j = 0; j < 4; ++j) acc4[i][j] = (f32x4){0.f, 0.f, 0.f, 0.f};
    for (int s = 0; s < 5; ++s) {
        short8 a[4], bb[4];
        #pragma unroll
        for (int i = 0; i < 4; ++i)
            a[i] = ldfrag(vbp, ((mg * 4 + i) * 5 + s) * 64 + lane);
        #pragma unroll
        for (int j = 0; j < 4; ++j)
            bb[j] = *(const short8*)(sh + (ng * 64 + j * 16 + rg) * LDP + s * 32 + kg * 8);
        #pragma unroll
        for (int i = 0; i < 4; ++i)
            #pragma unroll
            for (int j = 0; j < 4; ++j)
                acc4[i][j] = __builtin_amdgcn_mfma_f32_16x16x32_bf16(a[i], bb[j], acc4[i][j], 0, 0, 0);
    }
    __syncthreads();   // all P reads done

    // context -> LDS [n][kc] (stride LDH)
    #pragma unroll
    for (int i = 0; i < 4; ++i) {
        const int kc4 = mg * 64 + i * 16 + kg * 4;
        #pragma unroll
        for (int j = 0; j < 4; ++j) {
            const int n = ng * 64 + j * 16 + rg;
            uint2 pk;
            pk.x = pk2(acc4[i][j][0], acc4[i][j][1]);
            pk.y = pk2(acc4[i][j][2], acc4[i][j][3]);
            *(uint2*)(sh + n * LDH + kc4) = pk;
        }
    }
    __syncthreads();

    // ---------------- phase 5: G5 (K=256, M=512, two halves) ----------------
    #pragma unroll 1
    for (int h2 = 0; h2 < 2; ++h2) {
        f32x4 a5[4][4];
        #pragma unroll
        for (int i = 0; i < 4; ++i)
            #pragma unroll
            for (int j = 0; j < 4; ++j) a5[i][j] = (f32x4){0.f, 0.f, 0.f, 0.f};
        for (int S = 0; S < 8; ++S) {
            short8 a[4], bb[4];
            #pragma unroll
            for (int i = 0; i < 4; ++i)
                a[i] = ldfrag(wup, ((h2 * 16 + mg * 4 + i) * 8 + S) * 64 + lane);
            #pragma unroll
            for (int j = 0; j < 4; ++j)
                bb[j] = *(const short8*)(sh + (ng * 64 + j * 16 + rg) * LDH + S * 32 + kg * 8);
            #pragma unroll
            for (int i = 0; i < 4; ++i)
                #pragma unroll
                for (int j = 0; j < 4; ++j)
                    a5[i][j] = __builtin_amdgcn_mfma_f32_16x16x32_bf16(a[i], bb[j], a5[i][j], 0, 0, 0);
        }
        #pragma unroll
        for (int i = 0; i < 4; ++i) {
            const int c4 = h2 * 256 + mg * 64 + i * 16 + kg * 4;
            const f32x4 bv = *(const f32x4*)(bu + c4);
            #pragma unroll
            for (int j = 0; j < 4; ++j) {
                const int n = n0 + ng * 64 + j * 16 + rg;
                ob[(long)(c4 + 0) * NPX + n] = fmaxf(a5[i][j][0] + bv.x, 0.f);
                ob[(long)(c4 + 1) * NPX + n] = fmaxf(a5[i][j][1] + bv.y, 0.f);
                ob[(long)(c4 + 2) * NPX + n] = fmaxf(a5[i][j][2] + bv.z, 0.f);
                ob[(long)(c4 + 3) * NPX + n] = fmaxf(a5[i][j][3] + bv.w, 0.f);
            }
        }
    }
}

// ---------------------------------------------------------------------------
// kv1: grid (64, NB) x 192 thr; block = 4 kc, lane = kp (coalesced proxy).
// hiddenT[b][kp][kc] = relu(w_o1.proxy + b_o1)   (fp32, transposed)
// vp = packed A-frags of vT[kc][kp] (NS=5), kp>=150 zeroed.
// ---------------------------------------------------------------------------
__global__ __launch_bounds__(192)
void kv1_kernel(const float* __restrict__ proxy,
                const float* __restrict__ w_o1, const float* __restrict__ b_o1,
                const float* __restrict__ w_d,  const float* __restrict__ b_d,
                float* __restrict__ hiddenT, u16* __restrict__ vp)
{
    const int kc0 = blockIdx.x * 4;
    const int b   = blockIdx.y;
    const int kp  = threadIdx.x;   // 0..191
    float ah[4] = {0.f, 0.f, 0.f, 0.f}, av[4] = {0.f, 0.f, 0.f, 0.f};
    const float* px = proxy + (long)b * CIN * KP + (kp < KP ? kp : 0);
    for (int c = 0; c < CIN; ++c) {
        const float p = px[(long)c * KP];
        #pragma unroll
        for (int q = 0; q < 4; ++q) {
            ah[q] += w_o1[(long)(kc0 + q) * CIN + c] * p;
            av[q] += w_d [(long)(kc0 + q) * CIN + c] * p;
        }
    }
    if (kp < 160) {
        #pragma unroll
        for (int q = 0; q < 4; ++q) {
            const int kc = kc0 + q;
            const float hv = (kp < KP) ? fmaxf(ah[q] + b_o1[kc], 0.f) : 0.f;
            const float vv = (kp < KP) ? fmaxf(av[q] + b_d[kc], 0.f) : 0.f;
            hiddenT[((long)b * 160 + kp) * KC + kc] = hv;
            const int idx = (((kc >> 4) * 5 + (kp >> 5)) * 64 +
                             ((kp >> 3) & 3) * 16 + (kc & 15)) * 8 + (kp & 7);
            vp[(long)b * 40960 + idx] = f2bf(vv);
        }
    }
}

// ---------------------------------------------------------------------------
// kv2: grid (20, NB) x 256 thr; block = 8 kp rows; lane = kc.
// keyp = packed A-frags of key[kp][kc] (NS=8), kp>=150 zeroed.
// All loads coalesced (wo2T) or LDS-broadcast (hidden row).
// ---------------------------------------------------------------------------
__global__ __launch_bounds__(256)
void kv2_kernel(const float* __restrict__ hiddenT, const float* __restrict__ wo2T,
                const float* __restrict__ b_o2, u16* __restrict__ keyp)
{
    __shared__ float hl[8][KC];
    const int kp0 = blockIdx.x * 8;
    const int b   = blockIdx.y;
    const int kc  = threadIdx.x;
    #pragma unroll
    for (int q = 0; q < 8; ++q)
        hl[q][kc] = hiddenT[((long)b * 160 + kp0 + q) * KC + kc];
    __syncthreads();
    float acc[8] = {0.f, 0.f, 0.f, 0.f, 0.f, 0.f, 0.f, 0.f};
    for (int c = 0; c < KC; ++c) {
        const float w = wo2T[(long)c * KC + kc];
        #pragma unroll
        for (int q = 0; q < 8; ++q) acc[q] += w * hl[q][c];
    }
    const float bb = b_o2[kc];
    #pragma unroll
    for (int q = 0; q < 8; ++q) {
        const int kp = kp0 + q;
        const float v = (kp < KP) ? fmaxf(acc[q] + bb, 0.f) : 0.f;
        const int idx = (((kp >> 4) * 8 + (kc >> 5)) * 64 +
                         ((kc >> 3) & 3) * 16 + (kp & 15)) * 8 + (kc & 7);
        keyp[(long)b * 40960 + idx] = f2bf(v);
    }
}

// ---------------------------------------------------------------------------
// prep: pack wp1/wp2/wu into MFMA A-frag order (bf16) + transpose w_o2 (fp32).
// dest idx i -> j=i&7, l=(i>>3)&63, S, R; src = W[R*16+(l&15)][S*32+(l>>4)*8+j]
// ---------------------------------------------------------------------------
__global__ __launch_bounds__(256)
void prep_w(const float* __restrict__ w_p1, const float* __restrict__ w_p2,
            const float* __restrict__ w_u,  const float* __restrict__ w_o2,
            u16* __restrict__ wp1p, u16* __restrict__ wp2p,
            u16* __restrict__ wup, float* __restrict__ wo2T)
{
    const int i = blockIdx.x * 256 + threadIdx.x;   // < 131072
    const int j = i & 7, l = (i >> 3) & 63;
    {   // wp1: M=256, K=512, NS=16
        const int S = (i >> 9) & 15, R = i >> 13;
        wp1p[i] = f2bf(w_p1[(long)(R * 16 + (l & 15)) * CIN + S * 32 + ((l >> 4) << 3) + j]);
    }
    {   // wu: M=512, K=256, NS=8
        const int S = (i >> 9) & 7, R = i >> 12;
        wup[i] = f2bf(w_u[(long)(R * 16 + (l & 15)) * KC + S * 32 + ((l >> 4) << 3) + j]);
    }
    if (i < 65536) {
        // wp2: M=256, K=256, NS=8
        const int S = (i >> 9) & 7, R = i >> 12;
        wp2p[i] = f2bf(w_p2[(long)(R * 16 + (l & 15)) * KC + S * 32 + ((l >> 4) << 3) + j]);
        // wo2T[c][kc] = w_o2[kc][c]
        const int c = i >> 8, kc = i & 255;
        wo2T[i] = w_o2[(long)kc * KC + c];
    }
}

extern "C" void kernel_launch(void* const* d_in, const int* in_sizes, int n_in,
                              void* d_out, int out_size, void* d_ws, size_t ws_size,
                              hipStream_t stream)
{
    const float* x     = (const float*)d_in[0];
    const float* proxy = (const float*)d_in[1];
    const float* w_p1  = (const float*)d_in[2];
    const float* b_p1  = (const float*)d_in[3];
    const float* w_p2  = (const float*)d_in[4];
    const float* b_p2  = (const float*)d_in[5];
    const float* w_o1  = (const float*)d_in[6];
    const float* b_o1  = (const float*)d_in[7];
    const float* w_o2  = (const float*)d_in[8];
    const float* b_o2  = (const float*)d_in[9];
    const float* w_d   = (const float*)d_in[10];
    const float* b_d   = (const float*)d_in[11];
    const float* w_u   = (const float*)d_in[12];
    const float* b_u   = (const float*)d_in[13];
    float* out = (float*)d_out;
    (void)in_sizes; (void)n_in; (void)out_size; (void)ws_size;

    char* ws = (char*)d_ws;
    size_t off = 0;
    auto alloc = [&](size_t bytes) { size_t o = off; off += (bytes + 255) & ~(size_t)255; return o; };

    u16*   wp1p    = (u16*)  (ws + alloc((size_t)131072 * 2));
    u16*   wp2p    = (u16*)  (ws + alloc((size_t)65536 * 2));
    u16*   wup     = (u16*)  (ws + alloc((size_t)131072 * 2));
    float* wo2T    = (float*)(ws + alloc((size_t)65536 * 4));
    u16*   keyp    = (u16*)  (ws + alloc((size_t)NB * 40960 * 2));
    u16*   vp      = (u16*)  (ws + alloc((size_t)NB * 40960 * 2));
    float* hiddenT = (float*)(ws + alloc((size_t)NB * 160 * KC * 4));

    prep_w<<<512, 256, 0, stream>>>(w_p1, w_p2, w_u, w_o2, wp1p, wp2p, wup, wo2T);
    kv1_kernel<<<dim3(64, NB), 192, 0, stream>>>(proxy, w_o1, b_o1, w_d, b_d, hiddenT, vp);
    kv2_kernel<<<dim3(20, NB), 256, 0, stream>>>(hiddenT, wo2T, b_o2, keyp);

    fused_kernel<<<dim3(NPX / 128, 1, NB), 512, 0, stream>>>(
        wp1p, x, wp2p, b_p1, b_p2, keyp, vp, wup, b_u, out);
}

// Round 6
// 173.128 us; speedup vs baseline: 1.7825x; 1.7825x over previous
//
#include <hip/hip_runtime.h>
#include <hip/hip_bf16.h>

#define NB   4      // batch
#define CIN  512    // in channels
#define NPX  16384  // H*W
#define KC   256    // key channels
#define KP   150    // proxy regions

// LDS row strides (u16 units). Multiples of 8 (16B alignment for b128),
// ≡4 mod 32 dwords so consecutive rows shift banks -> b128 reads at floor.
#define LDH  264    // H1/Q/CX rows [128][256] padded
#define LDP  200    // P rows [128][160] padded
#define LDX  72     // XB rows [128][64] padded
#define SHSZ 33792  // u16: 128*264 = 67584 B total LDS
#define XBOF 15360  // XB dbuf base (2 x 9216 u16), overlaid inside H1 region

typedef __attribute__((ext_vector_type(8))) short short8;
typedef __attribute__((ext_vector_type(4))) float f32x4;
typedef __attribute__((ext_vector_type(4))) unsigned int u32x4;
typedef unsigned short u16;

__device__ __forceinline__ u16 f2bf(float f) {
    unsigned int u = __float_as_uint(f);
    return (u16)((u + 0x7FFFu + ((u >> 16) & 1u)) >> 16);
}
__device__ __forceinline__ unsigned pk2(float a, float b) {
    return (unsigned)f2bf(a) | ((unsigned)f2bf(b) << 16);
}
// fragment load from pre-packed global: idx = (R*NS+S)*64 + lane
__device__ __forceinline__ short8 ldfrag(const u16* __restrict__ p, int idx) {
    return *(const short8*)(p + ((long)idx << 3));
}

// ===========================================================================
// Fused: x(fp32) -> G1 -> G2 -> G3 -> softmax -> G4 -> G5 -> out(fp32)
// per 128-pixel tile. 512 thr = 8 waves (4 mg x 2 ng). 66KB LDS, 2 blk/CU.
// A-operands as packed frags from global (L2). Register budget engineered
// for the (512,4) 128-reg cap: acc 64 (AGPR) + a[4] + single bb + xr[8].
// ===========================================================================
__global__ __launch_bounds__(512, 4)
void fused_kernel(const u16* __restrict__ wp1p, const float* __restrict__ xg,
                  const u16* __restrict__ wp2p, const float* __restrict__ bp1,
                  const float* __restrict__ bp2, const u16* __restrict__ keyp,
                  const u16* __restrict__ vp, const u16* __restrict__ wup,
                  const float* __restrict__ bu, float* __restrict__ outg)
{
    __shared__ u16 sh[SHSZ];

    const int b  = blockIdx.z;
    const int n0 = blockIdx.x * 128;
    const int tid = threadIdx.x, lane = tid & 63, wid = tid >> 6;
    const int rg = lane & 15, kg = lane >> 4;
    const int mg = wid >> 1, ng = wid & 1;

    const float* xb = xg + (long)b * CIN * NPX;
    float* ob       = outg + (long)b * CIN * NPX;
    const u16* kyp  = keyp + (long)b * 40960;
    const u16* vbp  = vp   + (long)b * 40960;

    // ------------------------- phase 1: G1 (K=512) -------------------------
    const int sxn = tid & 127, sxk = tid >> 7;
    const float* xsrc = xb + (long)(sxk * 16) * NPX + n0 + sxn;
    u16* XB = sh + XBOF;

    float xr[8];
    auto LOADH = [&](int kt, int h) {
        #pragma unroll
        for (int e = 0; e < 8; ++e)
            xr[e] = xsrc[(long)(kt * 64 + h * 8 + e) * NPX];
    };
    auto WRITEH = [&](int buf, int h) {
        u32x4 v;
        v.x = pk2(xr[0], xr[1]); v.y = pk2(xr[2], xr[3]);
        v.z = pk2(xr[4], xr[5]); v.w = pk2(xr[6], xr[7]);
        *(u32x4*)(XB + buf * 9216 + sxn * LDX + (sxk * 2 + h) * 8) = v;
    };

    f32x4 acc[4][4];
    #pragma unroll
    for (int i = 0; i < 4; ++i)
        #pragma unroll
        for (int j = 0; j < 4; ++j) acc[i][j] = (f32x4){0.f, 0.f, 0.f, 0.f};

    LOADH(0, 0); WRITEH(0, 0); LOADH(0, 1); WRITEH(0, 1);
    __syncthreads();

    #pragma unroll 1
    for (int kt = 0; kt < 8; ++kt) {
        const int buf = kt & 1;
        if (kt < 7) LOADH(kt + 1, 0);
        #pragma unroll 1
        for (int s = 0; s < 2; ++s) {
            short8 a[4];
            #pragma unroll
            for (int i = 0; i < 4; ++i)
                a[i] = ldfrag(wp1p, ((mg * 4 + i) * 16 + kt * 2 + s) * 64 + lane);
            #pragma unroll
            for (int j = 0; j < 4; ++j) {
                short8 bb = *(const short8*)(XB + buf * 9216 + (ng * 64 + j * 16 + rg) * LDX + (s * 4 + kg) * 8);
                #pragma unroll
                for (int i = 0; i < 4; ++i)
                    acc[i][j] = __builtin_amdgcn_mfma_f32_16x16x32_bf16(a[i], bb, acc[i][j], 0, 0, 0);
            }
            if (s == 0 && kt < 7) { WRITEH(buf ^ 1, 0); LOADH(kt + 1, 1); }
        }
        if (kt < 7) WRITEH(buf ^ 1, 1);
        __syncthreads();
    }

    // h1 -> LDS [n][kc] (stride LDH), bias+relu
    #pragma unroll
    for (int i = 0; i < 4; ++i) {
        const int kc4 = mg * 64 + i * 16 + kg * 4;
        const f32x4 bv = *(const f32x4*)(bp1 + kc4);
        #pragma unroll
        for (int j = 0; j < 4; ++j) {
            const int n = ng * 64 + j * 16 + rg;
            uint2 pk;
            pk.x = pk2(fmaxf(acc[i][j][0] + bv.x, 0.f), fmaxf(acc[i][j][1] + bv.y, 0.f));
            pk.y = pk2(fmaxf(acc[i][j][2] + bv.z, 0.f), fmaxf(acc[i][j][3] + bv.w, 0.f));
            *(uint2*)(sh + n * LDH + kc4) = pk;
        }
    }
    __syncthreads();

    // ------------------------- phase 2: G2 (K=256) -------------------------
    f32x4 acc2[4][4];
    #pragma unroll
    for (int i = 0; i < 4; ++i)
        #pragma unroll
        for (int j = 0; j < 4; ++j) acc2[i][j] = (f32x4){0.f, 0.f, 0.f, 0.f};

    #pragma unroll 1
    for (int S = 0; S < 8; ++S) {
        short8 a[4];
        #pragma unroll
        for (int i = 0; i < 4; ++i)
            a[i] = ldfrag(wp2p, ((mg * 4 + i) * 8 + S) * 64 + lane);
        #pragma unroll
        for (int j = 0; j < 4; ++j) {
            short8 bb = *(const short8*)(sh + (ng * 64 + j * 16 + rg) * LDH + S * 32 + kg * 8);
            #pragma unroll
            for (int i = 0; i < 4; ++i)
                acc2[i][j] = __builtin_amdgcn_mfma_f32_16x16x32_bf16(a[i], bb, acc2[i][j], 0, 0, 0);
        }
    }
    __syncthreads();   // all H1 reads done

    // q2 -> same LDS region, bias+relu
    #pragma unroll
    for (int i = 0; i < 4; ++i) {
        const int kc4 = mg * 64 + i * 16 + kg * 4;
        const f32x4 bv = *(const f32x4*)(bp2 + kc4);
        #pragma unroll
        for (int j = 0; j < 4; ++j) {
            const int n = ng * 64 + j * 16 + rg;
            uint2 pk;
            pk.x = pk2(fmaxf(acc2[i][j][0] + bv.x, 0.f), fmaxf(acc2[i][j][1] + bv.y, 0.f));
            pk.y = pk2(fmaxf(acc2[i][j][2] + bv.z, 0.f), fmaxf(acc2[i][j][3] + bv.w, 0.f));
            *(uint2*)(sh + n * LDH + kc4) = pk;
        }
    }
    __syncthreads();

    // ------------------- phase 3: G3 + in-register softmax ------------------
    // wave wid owns pixels n = wid*16 + rg
    f32x4 s1[10];
    #pragma unroll
    for (int i = 0; i < 10; ++i) s1[i] = (f32x4){0.f, 0.f, 0.f, 0.f};
    #pragma unroll 1
    for (int s = 0; s < 8; ++s) {
        short8 bq = *(const short8*)(sh + (wid * 16 + rg) * LDH + s * 32 + kg * 8);
        #pragma unroll
        for (int i = 0; i < 10; ++i) {
            short8 a = ldfrag(kyp, (i * 8 + s) * 64 + lane);
            s1[i] = __builtin_amdgcn_mfma_f32_16x16x32_bf16(a, bq, s1[i], 0, 0, 0);
        }
    }
    float mx = -3.0e38f;
    #pragma unroll
    for (int i = 0; i < 9; ++i)
        #pragma unroll
        for (int r = 0; r < 4; ++r) mx = fmaxf(mx, s1[i][r]);
    #pragma unroll
    for (int r = 0; r < 4; ++r) if (kg * 4 + r < 6) mx = fmaxf(mx, s1[9][r]);
    mx = fmaxf(mx, __shfl_xor(mx, 16));
    mx = fmaxf(mx, __shfl_xor(mx, 32));
    float l = 0.f;
    #pragma unroll
    for (int i = 0; i < 10; ++i)
        #pragma unroll
        for (int r = 0; r < 4; ++r) {
            const bool valid = (i < 9) || (kg * 4 + r < 6);
            float e = valid ? __expf((s1[i][r] - mx) * 0.0625f) : 0.f;
            s1[i][r] = e; l += e;
        }
    l += __shfl_xor(l, 16);
    l += __shfl_xor(l, 32);
    const float inv = 1.f / l;
    __syncthreads();   // all Q reads done

    // P -> LDS [n][kp] (stride LDP), normalized bf16
    #pragma unroll
    for (int i = 0; i < 10; ++i) {
        uint2 pk;
        pk.x = pk2(s1[i][0] * inv, s1[i][1] * inv);
        pk.y = pk2(s1[i][2] * inv, s1[i][3] * inv);
        *(uint2*)(sh + (wid * 16 + rg) * LDP + i * 16 + kg * 4) = pk;
    }
    __syncthreads();

    // ------------------------- phase 4: G4 (K=160) -------------------------
    f32x4 acc4[4][4];
    #pragma unroll
    for (int i = 0; i < 4; ++i)
        #pragma unroll
        for (int j = 0; j < 4; ++j) acc4[i][j] = (f32x4){0.f, 0.f, 0.f, 0.f};
    #pragma unroll 1
    for (int s = 0; s < 5; ++s) {
        short8 a[4];
        #pragma unroll
        for (int i = 0; i < 4; ++i)
            a[i] = ldfrag(vbp, ((mg * 4 + i) * 5 + s) * 64 + lane);
        #pragma unroll
        for (int j = 0; j < 4; ++j) {
            short8 bb = *(const short8*)(sh + (ng * 64 + j * 16 + rg) * LDP + s * 32 + kg * 8);
            #pragma unroll
            for (int i = 0; i < 4; ++i)
                acc4[i][j] = __builtin_amdgcn_mfma_f32_16x16x32_bf16(a[i], bb, acc4[i][j], 0, 0, 0);
        }
    }
    __syncthreads();   // all P reads done

    // context -> LDS [n][kc] (stride LDH)
    #pragma unroll
    for (int i = 0; i < 4; ++i) {
        const int kc4 = mg * 64 + i * 16 + kg * 4;
        #pragma unroll
        for (int j = 0; j < 4; ++j) {
            const int n = ng * 64 + j * 16 + rg;
            uint2 pk;
            pk.x = pk2(acc4[i][j][0], acc4[i][j][1]);
            pk.y = pk2(acc4[i][j][2], acc4[i][j][3]);
            *(uint2*)(sh + n * LDH + kc4) = pk;
        }
    }
    __syncthreads();

    // ---------------- phase 5: G5 (K=256, M=512, two halves) ----------------
    #pragma unroll 1
    for (int h2 = 0; h2 < 2; ++h2) {
        f32x4 a5[4][4];
        #pragma unroll
        for (int i = 0; i < 4; ++i)
            #pragma unroll
            for (int j = 0; j < 4; ++j) a5[i][j] = (f32x4){0.f, 0.f, 0.f, 0.f};
        #pragma unroll 1
        for (int S = 0; S < 8; ++S) {
            short8 a[4];
            #pragma unroll
            for (int i = 0; i < 4; ++i)
                a[i] = ldfrag(wup, ((h2 * 16 + mg * 4 + i) * 8 + S) * 64 + lane);
            #pragma unroll
            for (int j = 0; j < 4; ++j) {
                short8 bb = *(const short8*)(sh + (ng * 64 + j * 16 + rg) * LDH + S * 32 + kg * 8);
                #pragma unroll
                for (int i = 0; i < 4; ++i)
                    a5[i][j] = __builtin_amdgcn_mfma_f32_16x16x32_bf16(a[i], bb, a5[i][j], 0, 0, 0);
            }
        }
        #pragma unroll
        for (int i = 0; i < 4; ++i) {
            const int c4 = h2 * 256 + mg * 64 + i * 16 + kg * 4;
            const f32x4 bv = *(const f32x4*)(bu + c4);
            #pragma unroll
            for (int j = 0; j < 4; ++j) {
                const int n = n0 + ng * 64 + j * 16 + rg;
                ob[(long)(c4 + 0) * NPX + n] = fmaxf(a5[i][j][0] + bv.x, 0.f);
                ob[(long)(c4 + 1) * NPX + n] = fmaxf(a5[i][j][1] + bv.y, 0.f);
                ob[(long)(c4 + 2) * NPX + n] = fmaxf(a5[i][j][2] + bv.z, 0.f);
                ob[(long)(c4 + 3) * NPX + n] = fmaxf(a5[i][j][3] + bv.w, 0.f);
            }
        }
    }
}

// ---------------------------------------------------------------------------
// kv1: grid (64, NB) x 192 thr; block = 4 kc, lane = kp (coalesced proxy).
// hiddenT[b][kp][kc] = relu(w_o1.proxy + b_o1)   (fp32, transposed)
// vp = packed A-frags of vT[kc][kp] (NS=5), kp>=150 zeroed.
// ---------------------------------------------------------------------------
__global__ __launch_bounds__(192)
void kv1_kernel(const float* __restrict__ proxy,
                const float* __restrict__ w_o1, const float* __restrict__ b_o1,
                const float* __restrict__ w_d,  const float* __restrict__ b_d,
                float* __restrict__ hiddenT, u16* __restrict__ vp)
{
    const int kc0 = blockIdx.x * 4;
    const int b   = blockIdx.y;
    const int kp  = threadIdx.x;   // 0..191
    float ah[4] = {0.f, 0.f, 0.f, 0.f}, av[4] = {0.f, 0.f, 0.f, 0.f};
    const float* px = proxy + (long)b * CIN * KP + (kp < KP ? kp : 0);
    for (int c = 0; c < CIN; ++c) {
        const float p = px[(long)c * KP];
        #pragma unroll
        for (int q = 0; q < 4; ++q) {
            ah[q] += w_o1[(long)(kc0 + q) * CIN + c] * p;
            av[q] += w_d [(long)(kc0 + q) * CIN + c] * p;
        }
    }
    if (kp < 160) {
        #pragma unroll
        for (int q = 0; q < 4; ++q) {
            const int kc = kc0 + q;
            const float hv = (kp < KP) ? fmaxf(ah[q] + b_o1[kc], 0.f) : 0.f;
            const float vv = (kp < KP) ? fmaxf(av[q] + b_d[kc], 0.f) : 0.f;
            hiddenT[((long)b * 160 + kp) * KC + kc] = hv;
            const int idx = (((kc >> 4) * 5 + (kp >> 5)) * 64 +
                             ((kp >> 3) & 3) * 16 + (kc & 15)) * 8 + (kp & 7);
            vp[(long)b * 40960 + idx] = f2bf(vv);
        }
    }
}

// ---------------------------------------------------------------------------
// kv2: grid (20, NB) x 256 thr; block = 8 kp rows; lane = kc.
// keyp = packed A-frags of key[kp][kc] (NS=8), kp>=150 zeroed.
// ---------------------------------------------------------------------------
__global__ __launch_bounds__(256)
void kv2_kernel(const float* __restrict__ hiddenT, const float* __restrict__ wo2T,
                const float* __restrict__ b_o2, u16* __restrict__ keyp)
{
    __shared__ float hl[8][KC];
    const int kp0 = blockIdx.x * 8;
    const int b   = blockIdx.y;
    const int kc  = threadIdx.x;
    #pragma unroll
    for (int q = 0; q < 8; ++q)
        hl[q][kc] = hiddenT[((long)b * 160 + kp0 + q) * KC + kc];
    __syncthreads();
    float acc[8] = {0.f, 0.f, 0.f, 0.f, 0.f, 0.f, 0.f, 0.f};
    for (int c = 0; c < KC; ++c) {
        const float w = wo2T[(long)c * KC + kc];
        #pragma unroll
        for (int q = 0; q < 8; ++q) acc[q] += w * hl[q][c];
    }
    const float bb = b_o2[kc];
    #pragma unroll
    for (int q = 0; q < 8; ++q) {
        const int kp = kp0 + q;
        const float v = (kp < KP) ? fmaxf(acc[q] + bb, 0.f) : 0.f;
        const int idx = (((kp >> 4) * 8 + (kc >> 5)) * 64 +
                         ((kc >> 3) & 3) * 16 + (kp & 15)) * 8 + (kc & 7);
        keyp[(long)b * 40960 + idx] = f2bf(v);
    }
}

// ---------------------------------------------------------------------------
// prep: pack wp1/wp2/wu into MFMA A-frag order (bf16) + transpose w_o2 (fp32).
// ---------------------------------------------------------------------------
__global__ __launch_bounds__(256)
void prep_w(const float* __restrict__ w_p1, const float* __restrict__ w_p2,
            const float* __restrict__ w_u,  const float* __restrict__ w_o2,
            u16* __restrict__ wp1p, u16* __restrict__ wp2p,
            u16* __restrict__ wup, float* __restrict__ wo2T)
{
    const int i = blockIdx.x * 256 + threadIdx.x;   // < 131072
    const int j = i & 7, l = (i >> 3) & 63;
    {   // wp1: M=256, K=512, NS=16
        const int S = (i >> 9) & 15, R = i >> 13;
        wp1p[i] = f2bf(w_p1[(long)(R * 16 + (l & 15)) * CIN + S * 32 + ((l >> 4) << 3) + j]);
    }
    {   // wu: M=512, K=256, NS=8
        const int S = (i >> 9) & 7, R = i >> 12;
        wup[i] = f2bf(w_u[(long)(R * 16 + (l & 15)) * KC + S * 32 + ((l >> 4) << 3) + j]);
    }
    if (i < 65536) {
        // wp2: M=256, K=256, NS=8
        const int S = (i >> 9) & 7, R = i >> 12;
        wp2p[i] = f2bf(w_p2[(long)(R * 16 + (l & 15)) * KC + S * 32 + ((l >> 4) << 3) + j]);
        // wo2T[c][kc] = w_o2[kc][c]
        const int c = i >> 8, kc = i & 255;
        wo2T[i] = w_o2[(long)kc * KC + c];
    }
}

extern "C" void kernel_launch(void* const* d_in, const int* in_sizes, int n_in,
                              void* d_out, int out_size, void* d_ws, size_t ws_size,
                              hipStream_t stream)
{
    const float* x     = (const float*)d_in[0];
    const float* proxy = (const float*)d_in[1];
    const float* w_p1  = (const float*)d_in[2];
    const float* b_p1  = (const float*)d_in[3];
    const float* w_p2  = (const float*)d_in[4];
    const float* b_p2  = (const float*)d_in[5];
    const float* w_o1  = (const float*)d_in[6];
    const float* b_o1  = (const float*)d_in[7];
    const float* w_o2  = (const float*)d_in[8];
    const float* b_o2  = (const float*)d_in[9];
    const float* w_d   = (const float*)d_in[10];
    const float* b_d   = (const float*)d_in[11];
    const float* w_u   = (const float*)d_in[12];
    const float* b_u   = (const float*)d_in[13];
    float* out = (float*)d_out;
    (void)in_sizes; (void)n_in; (void)out_size; (void)ws_size;

    char* ws = (char*)d_ws;
    size_t off = 0;
    auto alloc = [&](size_t bytes) { size_t o = off; off += (bytes + 255) & ~(size_t)255; return o; };

    u16*   wp1p    = (u16*)  (ws + alloc((size_t)131072 * 2));
    u16*   wp2p    = (u16*)  (ws + alloc((size_t)65536 * 2));
    u16*   wup     = (u16*)  (ws + alloc((size_t)131072 * 2));
    float* wo2T    = (float*)(ws + alloc((size_t)65536 * 4));
    u16*   keyp    = (u16*)  (ws + alloc((size_t)NB * 40960 * 2));
    u16*   vp      = (u16*)  (ws + alloc((size_t)NB * 40960 * 2));
    float* hiddenT = (float*)(ws + alloc((size_t)NB * 160 * KC * 4));

    prep_w<<<512, 256, 0, stream>>>(w_p1, w_p2, w_u, w_o2, wp1p, wp2p, wup, wo2T);
    kv1_kernel<<<dim3(64, NB), 192, 0, stream>>>(proxy, w_o1, b_o1, w_d, b_d, hiddenT, vp);
    kv2_kernel<<<dim3(20, NB), 256, 0, stream>>>(hiddenT, wo2T, b_o2, keyp);

    fused_kernel<<<dim3(NPX / 128, 1, NB), 512, 0, stream>>>(
        wp1p, x, wp2p, b_p1, b_p2, keyp, vp, wup, b_u, out);
}